// Round 5
// baseline (662.404 us; speedup 1.0000x reference)
//
#include <hip/hip_runtime.h>

typedef unsigned short bf_t;
typedef unsigned int u32;
typedef short short8 __attribute__((ext_vector_type(8)));
typedef float f32x4 __attribute__((ext_vector_type(4)));

#define NB 8
#define CC 128
#define NN 9216
#define EE 16

__device__ __forceinline__ float b2f(bf_t u){ return __uint_as_float(((u32)u)<<16); }
__device__ __forceinline__ bf_t f2b(float f){
  u32 u = __float_as_uint(f);
  u = (u + 0x7fffu + ((u>>16)&1u)) >> 16;
  return (bf_t)u;
}
__device__ __forceinline__ float gelu_f(float x){ return 0.5f*x*(1.f+erff(x*0.70710678118654752f)); }
__device__ __forceinline__ float red16(float v){
  #pragma unroll
  for (int m=1;m<16;m<<=1) v += __shfl_xor(v, m, 16);
  return v;
}
__device__ __forceinline__ float grs(float var){
  return rsqrtf(fmaxf(var + 1e-5f, 1e-8f));
}
// 8 consecutive fp32 -> bf16x8 MFMA fragment
__device__ __forceinline__ short8 ldw8(const float* __restrict__ p){
  float4 a = *(const float4*)p;
  float4 b = *(const float4*)(p+4);
  short8 o;
  o[0]=(short)f2b(a.x); o[1]=(short)f2b(a.y); o[2]=(short)f2b(a.z); o[3]=(short)f2b(a.w);
  o[4]=(short)f2b(b.x); o[5]=(short)f2b(b.y); o[6]=(short)f2b(b.z); o[7]=(short)f2b(b.w);
  return o;
}
__device__ __forceinline__ void ld16(const float* __restrict__ p, float* f){
  #pragma unroll
  for (int i=0;i<4;i++){
    float4 v = *(const float4*)(p + 4*i);
    f[4*i]=v.x; f[4*i+1]=v.y; f[4*i+2]=v.z; f[4*i+3]=v.w;
  }
}

// ---------------- zero hyper accumulator ----------------
__global__ __launch_bounds__(256) void k_zero(float* p){
  int i = blockIdx.x*256 + threadIdx.x;
  if (i < NB*EE*CC) p[i] = 0.f;
}

// ---- node LN (over c) + hyperedge aggregation, all fp32 I/O.
//      fm [B,C,N] f32 -> nln [B,C,N] f32 (into d_out, no transpose)
//      + atomicAdd partials of hacc[e][c] = sum_n sc[n][e]*ln[n][c] ----
__global__ __launch_bounds__(256) void k_ln_agg(const float* __restrict__ fm,
                                                const float* __restrict__ g,
                                                const float* __restrict__ bb,
                                                const float* __restrict__ sc,
                                                float* __restrict__ nln,
                                                float* __restrict__ hacc){
  int b = blockIdx.y, n0 = blockIdx.x*64, tid = threadIdx.x;
  __shared__ float xs[128*65];              // [c][n] tile, pad 65
  __shared__ float scs[64][17];             // [n][e]
  __shared__ float ps[4][64], pq[4][64], mrs[2][64];
  const float* base = fm + (size_t)b*CC*NN + n0;
  #pragma unroll
  for (int p=0;p<8;p++){
    int idx = tid + p*256;                  // 0..2047 float4s
    int c = idx>>4, n4 = (idx&15)*4;
    float4 v = *(const float4*)(base + (size_t)c*NN + n4);
    xs[c*65 + n4+0] = v.x; xs[c*65 + n4+1] = v.y;
    xs[c*65 + n4+2] = v.z; xs[c*65 + n4+3] = v.w;
  }
  { // sc tile: 64 n x 16 e
    int n = tid>>2, e4 = (tid&3)*4;
    float4 sv = *(const float4*)(sc + ((size_t)(b*NN + n0 + n))*EE + e4);
    scs[n][e4+0] = sv.x; scs[n][e4+1] = sv.y;
    scs[n][e4+2] = sv.z; scs[n][e4+3] = sv.w;
  }
  __syncthreads();
  {
    int cg = tid>>6, n = tid&63;
    float s=0.f, q=0.f;
    #pragma unroll
    for (int c=0;c<32;c++){ float v = xs[(cg*32+c)*65 + n]; s+=v; q+=v*v; }
    ps[cg][n]=s; pq[cg][n]=q;
  }
  __syncthreads();
  if (tid < 64){
    float S = ps[0][tid]+ps[1][tid]+ps[2][tid]+ps[3][tid];
    float Q = pq[0][tid]+pq[1][tid]+pq[2][tid]+pq[3][tid];
    float m = S*(1.f/128.f);
    float var = Q*(1.f/128.f) - m*m;
    mrs[0][tid] = m; mrs[1][tid] = grs(var);
  }
  __syncthreads();
  // normalize, write f32 c-major to global, keep LN values in xs
  #pragma unroll
  for (int p=0;p<8;p++){
    int idx = tid + p*256;
    int c = idx>>4, n4 = (idx&15)*4;
    float gv = g[c], bv = bb[c];
    float4 o;
    float v0 = (xs[c*65+n4+0]-mrs[0][n4+0])*mrs[1][n4+0]*gv + bv;
    float v1 = (xs[c*65+n4+1]-mrs[0][n4+1])*mrs[1][n4+1]*gv + bv;
    float v2 = (xs[c*65+n4+2]-mrs[0][n4+2])*mrs[1][n4+2]*gv + bv;
    float v3 = (xs[c*65+n4+3]-mrs[0][n4+3])*mrs[1][n4+3]*gv + bv;
    o.x=v0; o.y=v1; o.z=v2; o.w=v3;
    xs[c*65+n4+0]=v0; xs[c*65+n4+1]=v1; xs[c*65+n4+2]=v2; xs[c*65+n4+3]=v3;
    *(float4*)(nln + ((size_t)(b*CC + c))*NN + n0 + n4) = o;
  }
  __syncthreads();
  // aggregation partials: thread handles c in {cp, cp+64}, e in {eh*4..+3}
  {
    int cp = tid&63, eh = tid>>6;
    float a0[4]={0,0,0,0}, a1[4]={0,0,0,0};
    for (int n=0;n<64;n++){
      float x0 = xs[cp*65 + n], x1 = xs[(cp+64)*65 + n];
      #pragma unroll
      for (int j=0;j<4;j++){
        float se = scs[n][eh*4+j];
        a0[j] += se*x0; a1[j] += se*x1;
      }
    }
    #pragma unroll
    for (int j=0;j<4;j++){
      float* hb = hacc + (size_t)(b*EE + eh*4 + j)*CC;
      atomicAdd(hb + cp, a0[j]);
      atomicAdd(hb + cp + 64, a1[j]);
    }
  }
}

// ---------------- in-LDS 16-row MFMA GEMM helper (fp32 weights) ----------------
__device__ __forceinline__ void gemm16(const bf_t* A, int SA,
                                       const float* __restrict__ W,
                                       const float* __restrict__ bias,
                                       bf_t* O, int SO, int Nout, int K,
                                       int act, int tid){
  int lane = tid&63, wid = tid>>6;
  int m16 = lane&15, quad = lane>>4;
  for (int n0 = wid*16; n0 < Nout; n0 += 64){
    f32x4 acc = {0.f,0.f,0.f,0.f};
    for (int k0=0;k0<K;k0+=32){
      short8 af = *(const short8*)(A + m16*SA + k0 + quad*8);
      short8 bfv = ldw8(W + (size_t)(n0+m16)*K + k0 + quad*8);
      acc = __builtin_amdgcn_mfma_f32_16x16x32_bf16(af, bfv, acc, 0, 0, 0);
    }
    int col = n0 + m16;
    float bv = bias[col];
    #pragma unroll
    for (int r=0;r<4;r++){
      float v = acc[r] + bv;
      if (act) v = gelu_f(v);
      O[(quad*4+r)*SO + col] = f2b(v);
    }
  }
}

#define SP1 136
#define SP2 264
#define SP3 392

// ---------------- edge transformer (per batch): hacc -> hyper_f, V, Kt, qbK ----------------
__global__ __launch_bounds__(256) void k_edge(const float* __restrict__ hacc,
    const float* w_in, const float* b_in, const float* w_out, const float* b_out,
    const float* w1, const float* b1, const float* w2, const float* b2v,
    const float* tg, const float* tb, const float* nhg, const float* nhb,
    const float* hpw, const float* hpb, const float* kvw, const float* kvbias,
    const float* qw, const float* qb,
    bf_t* __restrict__ hfw, bf_t* __restrict__ vws,
    float* __restrict__ Ktg, float* __restrict__ qbK){
  __shared__ __align__(16) bf_t hyp0[16*SP1];
  __shared__ __align__(16) bf_t qkvb[16*SP3];
  __shared__ __align__(16) bf_t aob [16*SP1];
  __shared__ __align__(16) bf_t xnb [16*SP1];
  __shared__ __align__(16) bf_t h1b [16*SP2];
  __shared__ __align__(16) bf_t t2b [16*SP1];
  __shared__ __align__(16) bf_t hfb [16*SP1];
  __shared__ __align__(16) bf_t kvo [16*SP2];
  int b = blockIdx.x, tid = threadIdx.x;

  #pragma unroll
  for (int p=0;p<8;p++){
    int idx = tid + p*256;          // 0..2047
    int e = idx>>7, c = idx&127;
    hyp0[e*SP1 + c] = f2b(hacc[(size_t)(b*EE + e)*CC + c]);
  }
  __syncthreads();
  gemm16(hyp0, SP1, w_in, b_in, qkvb, SP3, 384, 128, 0, tid);
  __syncthreads();
  {
    int part = tid&3, hq = tid>>2;
    int h = hq>>4, qi = hq&15;
    int dbase = h*32 + part*8;
    float qv[8];
    #pragma unroll
    for (int j=0;j<8;j++) qv[j] = b2f(qkvb[qi*SP3 + dbase + j]);
    float dot[16];
    #pragma unroll
    for (int kk=0;kk<16;kk++){
      float s = 0.f;
      #pragma unroll
      for (int j=0;j<8;j++) s += qv[j]*b2f(qkvb[kk*SP3 + 128 + dbase + j]);
      dot[kk] = s;
    }
    #pragma unroll
    for (int m=1;m<4;m<<=1){
      #pragma unroll
      for (int kk=0;kk<16;kk++) dot[kk] += __shfl_xor(dot[kk], m, 4);
    }
    const float sc1 = 0.17677669529663687f;  // 1/sqrt(32)
    float mx = -1e30f;
    #pragma unroll
    for (int kk=0;kk<16;kk++){ dot[kk] *= sc1; mx = fmaxf(mx, dot[kk]); }
    float sum = 0.f;
    #pragma unroll
    for (int kk=0;kk<16;kk++){ dot[kk] = __expf(dot[kk]-mx); sum += dot[kk]; }
    float inv = 1.f/sum;
    float ao[8] = {0,0,0,0,0,0,0,0};
    #pragma unroll
    for (int kk=0;kk<16;kk++){
      float p = dot[kk]*inv;
      #pragma unroll
      for (int j=0;j<8;j++) ao[j] += p*b2f(qkvb[kk*SP3 + 256 + dbase + j]);
    }
    #pragma unroll
    for (int j=0;j<8;j++) aob[qi*SP1 + dbase + j] = f2b(ao[j]);
  }
  __syncthreads();
  gemm16(aob, SP1, w_out, b_out, xnb, SP1, 128, 128, 0, tid);
  __syncthreads();
  {
    int e = tid>>4, i = tid&15;
    float v[8]; float s=0.f, q=0.f;
    #pragma unroll
    for (int j=0;j<8;j++){
      int c = i*8+j;
      v[j] = b2f(hyp0[e*SP1+c]) + b2f(xnb[e*SP1+c]);
      s += v[j]; q += v[j]*v[j];
    }
    s = red16(s); q = red16(q);
    float m = s*(1.f/128.f);
    float rs = grs(q*(1.f/128.f) - m*m);
    #pragma unroll
    for (int j=0;j<8;j++){
      int c = i*8+j;
      xnb[e*SP1+c] = f2b((v[j]-m)*rs*tg[c] + tb[c]);
    }
  }
  __syncthreads();
  gemm16(xnb, SP1, w1, b1, h1b, SP2, 256, 128, 1, tid);
  __syncthreads();
  gemm16(h1b, SP2, w2, b2v, aob, SP1, 128, 256, 0, tid);
  __syncthreads();
  {
    int e = tid>>4, i = tid&15;
    float v[8]; float s=0.f, q=0.f;
    #pragma unroll
    for (int j=0;j<8;j++){
      int c = i*8+j;
      v[j] = b2f(xnb[e*SP1+c]) + b2f(aob[e*SP1+c]);
      s += v[j]; q += v[j]*v[j];
    }
    s = red16(s); q = red16(q);
    float m = s*(1.f/128.f);
    float rs = grs(q*(1.f/128.f) - m*m);
    float s2=0.f, q2=0.f;
    #pragma unroll
    for (int j=0;j<8;j++){
      int c = i*8+j;
      v[j] = (v[j]-m)*rs*tg[c] + tb[c];
      s2 += v[j]; q2 += v[j]*v[j];
    }
    s2 = red16(s2); q2 = red16(q2);
    float m2 = s2*(1.f/128.f);
    float rs2 = grs(q2*(1.f/128.f) - m2*m2);
    #pragma unroll
    for (int j=0;j<8;j++){
      int c = i*8+j;
      t2b[e*SP1+c] = f2b((v[j]-m2)*rs2*nhg[c] + nhb[c]);
    }
  }
  __syncthreads();
  gemm16(t2b, SP1, hpw, hpb, hfb, SP1, 128, 128, 1, tid);
  __syncthreads();
  gemm16(hfb, SP1, kvw, kvbias, kvo, SP2, 256, 128, 0, tid);
  __syncthreads();
  #pragma unroll
  for (int p=0;p<8;p++){
    int idx = tid + p*256;
    int e = idx>>7, c = idx&127;
    size_t o = (size_t)(b*EE + e)*CC + c;
    hfw[o] = hfb[e*SP1 + c];
    vws[o] = kvo[e*SP2 + 128 + c];
  }
  #pragma unroll
  for (int p=0;p<8;p++){
    int idx = tid + p*256;
    int e = idx>>7, c = idx&127;
    float s = 0.f;
    for (int d=0; d<128; d++) s += b2f(kvo[e*SP2 + d]) * qw[d*128 + c];
    Ktg[(size_t)(b*EE + e)*CC + c] = s;
  }
  if (tid < 16){
    float s = 0.f;
    for (int d=0; d<128; d++) s += qb[d] * b2f(kvo[tid*SP2 + d]);
    qbK[b*EE + tid] = s;
  }
}

// -------- mega node kernel: cross-attn + intra + concat-LN + gate GEMM + gate-LN
//          + sigmoid + fuse + residual + OUTPUT PROJECTION (gelu), in place on
//          d_out [B,C,N] fp32 (nln in, final out), per-block 64-node tile. --------
__global__ __launch_bounds__(256) void k_meganode(
    float* __restrict__ io, const float* __restrict__ sc,
    const bf_t* __restrict__ hf, const bf_t* __restrict__ vw,
    const float* __restrict__ Ktg, const float* __restrict__ qbK,
    const float* __restrict__ nfg, const float* __restrict__ nfb,
    const float* __restrict__ gw, const float* __restrict__ gb,
    const float* __restrict__ glng, const float* __restrict__ glnb,
    const float* __restrict__ npw, const float* __restrict__ npb){
  int tid = threadIdx.x, lane = tid&63, wid = tid>>6;
  int m16 = lane&15, quad = lane>>4;
  int b = blockIdx.y, n0 = blockIdx.x*64;
  __shared__ __align__(16) bf_t xt[64*136];     // [n_local][c] bf16 tile
  __shared__ float hfs[16][132], vfs[16][132], kts[16][132];
  __shared__ float hfsT[128][20], vfsT[128][20];
  __shared__ float a_s[4][16][16];
  __shared__ float qbs[16];
  // stage node tile: fp32 c-major -> bf16 [n][c]
  #pragma unroll
  for (int p=0;p<8;p++){
    int idx = tid + p*256;                       // 0..2047 float4s
    int c = idx>>4, n4 = (idx&15)*4;
    float4 v = *(const float4*)(io + ((size_t)(b*CC + c))*NN + n0 + n4);
    xt[(n4+0)*136 + c] = f2b(v.x);
    xt[(n4+1)*136 + c] = f2b(v.y);
    xt[(n4+2)*136 + c] = f2b(v.z);
    xt[(n4+3)*136 + c] = f2b(v.w);
  }
  {
    const u32* hs = (const u32*)(hf + (size_t)b*EE*CC);
    const u32* vs = (const u32*)(vw + (size_t)b*EE*CC);
    #pragma unroll
    for (int p=0;p<4;p++){
      int idx = tid + p*256;       // 0..1023
      int e = idx>>6, c2 = (idx&63)*2;
      u32 hv = hs[idx], vv = vs[idx];
      float h0 = b2f((bf_t)(hv&0xffffu)), h1 = b2f((bf_t)(hv>>16));
      float v0 = b2f((bf_t)(vv&0xffffu)), v1 = b2f((bf_t)(vv>>16));
      hfs[e][c2] = h0; hfs[e][c2+1] = h1;
      vfs[e][c2] = v0; vfs[e][c2+1] = v1;
      hfsT[c2][e] = h0; hfsT[c2+1][e] = h1;
      vfsT[c2][e] = v0; vfsT[c2+1][e] = v1;
    }
    const float* kp = Ktg + (size_t)b*EE*CC;
    #pragma unroll
    for (int p=0;p<2;p++){
      int idx = tid + p*256;       // 0..511 float4s
      int e = idx>>5, c4 = (idx&31)*4;
      float4 kv = *(const float4*)(kp + e*CC + c4);
      kts[e][c4+0]=kv.x; kts[e][c4+1]=kv.y; kts[e][c4+2]=kv.z; kts[e][c4+3]=kv.w;
    }
    if (tid < 16) qbs[tid] = qbK[b*EE + tid];
  }
  __syncthreads();
  int rowA = wid*16 + m16;                       // local n of this lane's A-row
  size_t growA = (size_t)b*NN + n0 + rowA;
  float nl[4][8];
  #pragma unroll
  for (int kk=0;kk<4;kk++){
    short8 v = *(const short8*)(xt + rowA*136 + kk*32 + quad*8);
    #pragma unroll
    for (int j=0;j<8;j++) nl[kk][j] = b2f((bf_t)v[j]);
  }
  float dot[16];
  #pragma unroll
  for (int e=0;e<16;e++){
    float s = 0.f;
    #pragma unroll
    for (int kk=0;kk<4;kk++){
      int ch0 = kk*32 + quad*8;
      #pragma unroll
      for (int j=0;j<8;j++) s += nl[kk][j]*kts[e][ch0+j];
    }
    dot[e] = s;
  }
  #pragma unroll
  for (int e=0;e<16;e++){
    dot[e] += __shfl_xor(dot[e], 16);
    dot[e] += __shfl_xor(dot[e], 32);
    dot[e] = (dot[e] + qbs[e]) * 0.08838834764831845f;   // C^-0.5
  }
  float mx = -1e30f;
  #pragma unroll
  for (int e=0;e<16;e++) mx = fmaxf(mx, dot[e]);
  float sum = 0.f;
  #pragma unroll
  for (int e=0;e<16;e++){ dot[e] = __expf(dot[e]-mx); sum += dot[e]; }
  float inv = 1.f/sum;
  #pragma unroll
  for (int e=0;e<16;e++) dot[e] *= inv;
  if (quad == 0){
    #pragma unroll
    for (int e=0;e<16;e++) a_s[wid][m16][e] = dot[e];
  }
  float svA[16];
  ld16(sc + growA*EE, svA);
  float raw[8][8];
  float s = 0.f, q = 0.f;
  #pragma unroll
  for (int kk=0;kk<4;kk++){
    int ch0 = kk*32 + quad*8;
    #pragma unroll
    for (int j=0;j<8;j++){
      float v = 0.f;
      #pragma unroll
      for (int e=0;e<16;e++) v += svA[e]*hfs[e][ch0+j];
      raw[kk][j] = v; s += v; q += v*v;
    }
  }
  #pragma unroll
  for (int kk=4;kk<8;kk++){
    int ch0 = (kk-4)*32 + quad*8;
    #pragma unroll
    for (int j=0;j<8;j++){
      float v = 0.f;
      #pragma unroll
      for (int e=0;e<16;e++) v += dot[e]*vfs[e][ch0+j];
      raw[kk][j] = v; s += v; q += v*v;
    }
  }
  s += __shfl_xor(s, 16); s += __shfl_xor(s, 32);
  q += __shfl_xor(q, 16); q += __shfl_xor(q, 32);
  float mean = s*(1.f/256.f);
  float rstd = grs(q*(1.f/256.f) - mean*mean);
  short8 af[8];
  #pragma unroll
  for (int kk=0;kk<8;kk++){
    int kb = kk*32 + quad*8;
    short8 o;
    #pragma unroll
    for (int j=0;j<8;j++){
      float v = (raw[kk][j]-mean)*rstd*nfg[kb+j] + nfb[kb+j];
      o[j] = (short)f2b(v);
    }
    af[kk] = o;
  }
  __syncthreads();   // a_s visible
  // --- gate GEMM (K=256) ---
  f32x4 acc[8];
  #pragma unroll
  for (int t=0;t<8;t++){
    f32x4 a = {0.f,0.f,0.f,0.f};
    #pragma unroll
    for (int kk=0;kk<8;kk++){
      short8 bfv = ldw8(gw + (size_t)(t*16+m16)*256 + kk*32 + quad*8);
      a = __builtin_amdgcn_mfma_f32_16x16x32_bf16(af[kk], bfv, a, 0, 0, 0);
    }
    acc[t] = a;
  }
  float s2[4] = {0,0,0,0}, q2[4] = {0,0,0,0};
  #pragma unroll
  for (int t=0;t<8;t++){
    float bv = gb[t*16+m16];
    #pragma unroll
    for (int r=0;r<4;r++){
      float v = acc[t][r] + bv;
      acc[t][r] = v; s2[r] += v; q2[r] += v*v;
    }
  }
  #pragma unroll
  for (int r=0;r<4;r++){ s2[r] = red16(s2[r]); q2[r] = red16(q2[r]); }
  // --- per D-row: sigmoid gate, fuse, residual; update xt in place ---
  #pragma unroll
  for (int r=0;r<4;r++){
    float m2 = s2[r]*(1.f/128.f);
    float rs2 = grs(q2[r]*(1.f/128.f) - m2*m2);
    int rowD = wid*16 + quad*4 + r;
    size_t growD = (size_t)b*NN + n0 + rowD;
    float av[16];
    #pragma unroll
    for (int e=0;e<16;e++) av[e] = a_s[wid][quad*4+r][e];
    float svD[16];
    ld16(sc + growD*EE, svD);
    #pragma unroll
    for (int t=0;t<8;t++){
      int col = t*16 + m16;
      float it = 0.f, cr = 0.f;
      #pragma unroll
      for (int e4=0;e4<4;e4++){
        float4 h4 = *(const float4*)&hfsT[col][4*e4];
        float4 v4 = *(const float4*)&vfsT[col][4*e4];
        it += svD[4*e4+0]*h4.x + svD[4*e4+1]*h4.y + svD[4*e4+2]*h4.z + svD[4*e4+3]*h4.w;
        cr += av[4*e4+0]*v4.x + av[4*e4+1]*v4.y + av[4*e4+2]*v4.z + av[4*e4+3]*v4.w;
      }
      float z = (acc[t][r]-m2)*rs2*glng[col] + glnb[col];
      float g = 1.f/(1.f + __expf(-z));
      float nld = b2f(xt[rowD*136 + col]);
      xt[rowD*136 + col] = f2b(nld + g*it + (1.f-g)*cr);
    }
  }
  __syncthreads();
  // --- fused output projection: out[c][n] = gelu(sum_k npw[c][k]*upd[n][k] + npb[c])
  //     wave handles its own 16 nodes (all 128 c), writes fp32 in place. ---
  short8 bfu[4];
  #pragma unroll
  for (int kk=0;kk<4;kk++)
    bfu[kk] = *(const short8*)(xt + (wid*16 + m16)*136 + kk*32 + quad*8);
  #pragma unroll
  for (int mt=0;mt<8;mt++){
    f32x4 oacc = {0.f,0.f,0.f,0.f};
    #pragma unroll
    for (int kk=0;kk<4;kk++){
      short8 afw = ldw8(npw + (size_t)(mt*16+m16)*128 + kk*32 + quad*8);
      oacc = __builtin_amdgcn_mfma_f32_16x16x32_bf16(afw, bfu[kk], oacc, 0, 0, 0);
    }
    #pragma unroll
    for (int r=0;r<4;r++){
      int c = mt*16 + quad*4 + r;
      float v = gelu_f(oacc[r] + npb[c]);
      io[((size_t)(b*CC + c))*NN + n0 + wid*16 + m16] = v;
    }
  }
}

extern "C" void kernel_launch(void* const* d_in, const int* in_sizes, int n_in,
                              void* d_out, int out_size, void* d_ws, size_t ws_size,
                              hipStream_t stream){
  (void)in_sizes; (void)n_in; (void)out_size; (void)ws_size;
  const float* fm   = (const float*)d_in[0];
  const float* sc   = (const float*)d_in[1];
  const float* npg  = (const float*)d_in[2];
  const float* npb_ = (const float*)d_in[3];
  const float* w_in = (const float*)d_in[4];
  const float* b_in = (const float*)d_in[5];
  const float* w_out= (const float*)d_in[6];
  const float* b_out= (const float*)d_in[7];
  const float* w1   = (const float*)d_in[8];
  const float* b1   = (const float*)d_in[9];
  const float* w2   = (const float*)d_in[10];
  const float* b2v  = (const float*)d_in[11];
  const float* tg   = (const float*)d_in[12];
  const float* tb   = (const float*)d_in[13];
  const float* nhg  = (const float*)d_in[14];
  const float* nhb  = (const float*)d_in[15];
  const float* hpw  = (const float*)d_in[16];
  const float* hpb  = (const float*)d_in[17];
  const float* qw   = (const float*)d_in[18];
  const float* qb   = (const float*)d_in[19];
  const float* kvw  = (const float*)d_in[20];
  const float* kvb  = (const float*)d_in[21];
  const float* nfg  = (const float*)d_in[22];
  const float* nfb  = (const float*)d_in[23];
  const float* gw   = (const float*)d_in[24];
  const float* gb   = (const float*)d_in[25];
  const float* glng = (const float*)d_in[26];
  const float* glnb = (const float*)d_in[27];
  const float* npw  = (const float*)d_in[28];
  const float* npb2 = (const float*)d_in[29];

  // node tensor lives fp32 c-major [B,C,N] in d_out for its whole life.
  float* nln = (float*)d_out;

  // d_ws: only 197,120 bytes used.
  char* w = (char*)d_ws;
  float* hacc = (float*)(w);                   //  65,536 B
  float* Ktg  = (float*)(w + 65536);           //  65,536 B
  float* qbK  = (float*)(w + 131072);          //     512 B
  bf_t*  hfw  = (bf_t*) (w + 131584);          //  32,768 B
  bf_t*  vws  = (bf_t*) (w + 164352);          //  32,768 B (end 197,120)

  k_zero    <<<dim3(64),    dim3(256), 0, stream>>>(hacc);
  k_ln_agg  <<<dim3(144,8), dim3(256), 0, stream>>>(fm, npg, npb_, sc, nln, hacc);
  k_edge    <<<dim3(8),     dim3(256), 0, stream>>>(hacc, w_in,b_in,w_out,b_out,
                                                    w1,b1,w2,b2v, tg,tb, nhg,nhb,
                                                    hpw,hpb, kvw,kvb, qw,qb,
                                                    hfw, vws, Ktg, qbK);
  k_meganode<<<dim3(144,8), dim3(256), 0, stream>>>(nln, sc, hfw, vws, Ktg, qbK,
                                                    nfg, nfb, gw, gb, glng, glnb,
                                                    npw, npb2);
}

// Round 6
// 311.499 us; speedup vs baseline: 2.1265x; 2.1265x over previous
//
#include <hip/hip_runtime.h>

typedef unsigned short bf_t;
typedef unsigned int u32;
typedef short short8 __attribute__((ext_vector_type(8)));
typedef float f32x4 __attribute__((ext_vector_type(4)));

#define NB 8
#define CC 128
#define NN 9216
#define EE 16

__device__ __forceinline__ float b2f(bf_t u){ return __uint_as_float(((u32)u)<<16); }
__device__ __forceinline__ bf_t f2b(float f){
  u32 u = __float_as_uint(f);
  u = (u + 0x7fffu + ((u>>16)&1u)) >> 16;
  return (bf_t)u;
}
__device__ __forceinline__ u32 pk2(float a, float b){
  return (u32)f2b(a) | ((u32)f2b(b)<<16);
}
__device__ __forceinline__ float gelu_f(float x){ return 0.5f*x*(1.f+erff(x*0.70710678118654752f)); }
__device__ __forceinline__ float red16(float v){
  #pragma unroll
  for (int m=1;m<16;m<<=1) v += __shfl_xor(v, m, 16);
  return v;
}
__device__ __forceinline__ float grs(float var){
  return rsqrtf(fmaxf(var + 1e-5f, 1e-8f));
}
// 8 consecutive fp32 -> bf16x8 MFMA fragment (fallback path)
__device__ __forceinline__ short8 ldw8(const float* __restrict__ p){
  float4 a = *(const float4*)p;
  float4 b = *(const float4*)(p+4);
  short8 o;
  o[0]=(short)f2b(a.x); o[1]=(short)f2b(a.y); o[2]=(short)f2b(a.z); o[3]=(short)f2b(a.w);
  o[4]=(short)f2b(b.x); o[5]=(short)f2b(b.y); o[6]=(short)f2b(b.z); o[7]=(short)f2b(b.w);
  return o;
}

// ---------------- zero hyper accumulator ----------------
__global__ __launch_bounds__(256) void k_zero(float* p){
  int i = blockIdx.x*256 + threadIdx.x;
  if (i < NB*EE*CC) p[i] = 0.f;
}

// ---------------- convert gate / nproj weights to bf16 (PRE path) ----------------
__global__ __launch_bounds__(256) void k_cvtw(const float* __restrict__ gw,
                                              const float* __restrict__ npw,
                                              bf_t* __restrict__ gwb,
                                              bf_t* __restrict__ npwb){
  int i = blockIdx.x*256 + threadIdx.x;     // 0..16383
  gwb[i]        = f2b(gw[i]);
  gwb[i+16384]  = f2b(gw[i+16384]);
  npwb[i]       = f2b(npw[i]);
}

// ---- node LN (over c) + hyperedge aggregation, fp32 I/O.
//      fm [B,C,N] f32 -> nln [B,C,N] f32 (into d_out)
//      4 n-tiles per block; agg partials accumulated in regs, 1 atomic set/block ----
__global__ __launch_bounds__(256) void k_ln_agg(const float* __restrict__ fm,
                                                const float* __restrict__ g,
                                                const float* __restrict__ bb,
                                                const float* __restrict__ sc,
                                                float* __restrict__ nln,
                                                float* __restrict__ hacc){
  int b = blockIdx.y, tid = threadIdx.x;
  __shared__ float xs[128*65];              // [c][n] tile, pad 65
  __shared__ float scs[64][17];             // [n][e]
  __shared__ float ps[4][64], pq[4][64], mrs[2][64];
  int cp = tid&63, eh = tid>>6;
  float a0[4]={0,0,0,0}, a1[4]={0,0,0,0};
  for (int ts=0; ts<4; ts++){
    int n0 = (blockIdx.x*4 + ts)*64;
    const float* base = fm + (size_t)b*CC*NN + n0;
    #pragma unroll
    for (int p=0;p<8;p++){
      int idx = tid + p*256;                  // 0..2047 float4s
      int c = idx>>4, n4 = (idx&15)*4;
      float4 v = *(const float4*)(base + (size_t)c*NN + n4);
      xs[c*65 + n4+0] = v.x; xs[c*65 + n4+1] = v.y;
      xs[c*65 + n4+2] = v.z; xs[c*65 + n4+3] = v.w;
    }
    { int n = tid>>2, e4 = (tid&3)*4;
      float4 sv = *(const float4*)(sc + ((size_t)(b*NN + n0 + n))*EE + e4);
      scs[n][e4+0] = sv.x; scs[n][e4+1] = sv.y;
      scs[n][e4+2] = sv.z; scs[n][e4+3] = sv.w;
    }
    __syncthreads();
    { int cg = tid>>6, n = tid&63;
      float s=0.f, q=0.f;
      #pragma unroll
      for (int c=0;c<32;c++){ float v = xs[(cg*32+c)*65 + n]; s+=v; q+=v*v; }
      ps[cg][n]=s; pq[cg][n]=q;
    }
    __syncthreads();
    if (tid < 64){
      float S = ps[0][tid]+ps[1][tid]+ps[2][tid]+ps[3][tid];
      float Q = pq[0][tid]+pq[1][tid]+pq[2][tid]+pq[3][tid];
      float m = S*(1.f/128.f);
      mrs[0][tid] = m; mrs[1][tid] = grs(Q*(1.f/128.f) - m*m);
    }
    __syncthreads();
    #pragma unroll
    for (int p=0;p<8;p++){
      int idx = tid + p*256;
      int c = idx>>4, n4 = (idx&15)*4;
      float gv = g[c], bv = bb[c];
      float4 o;
      float v0 = (xs[c*65+n4+0]-mrs[0][n4+0])*mrs[1][n4+0]*gv + bv;
      float v1 = (xs[c*65+n4+1]-mrs[0][n4+1])*mrs[1][n4+1]*gv + bv;
      float v2 = (xs[c*65+n4+2]-mrs[0][n4+2])*mrs[1][n4+2]*gv + bv;
      float v3 = (xs[c*65+n4+3]-mrs[0][n4+3])*mrs[1][n4+3]*gv + bv;
      o.x=v0; o.y=v1; o.z=v2; o.w=v3;
      xs[c*65+n4+0]=v0; xs[c*65+n4+1]=v1; xs[c*65+n4+2]=v2; xs[c*65+n4+3]=v3;
      *(float4*)(nln + ((size_t)(b*CC + c))*NN + n0 + n4) = o;
    }
    __syncthreads();
    for (int n=0;n<64;n++){
      float x0 = xs[cp*65 + n], x1 = xs[(cp+64)*65 + n];
      #pragma unroll
      for (int j=0;j<4;j++){
        float se = scs[n][eh*4+j];
        a0[j] += se*x0; a1[j] += se*x1;
      }
    }
    __syncthreads();   // xs reused next tile
  }
  #pragma unroll
  for (int j=0;j<4;j++){
    float* hb = hacc + (size_t)(b*EE + eh*4 + j)*CC;
    atomicAdd(hb + cp, a0[j]);
    atomicAdd(hb + cp + 64, a1[j]);
  }
}

// ---------------- in-LDS 16-row MFMA GEMM helper (fp32 weights) ----------------
__device__ __forceinline__ void gemm16(const bf_t* A, int SA,
                                       const float* __restrict__ W,
                                       const float* __restrict__ bias,
                                       bf_t* O, int SO, int Nout, int K,
                                       int act, int tid){
  int lane = tid&63, wid = tid>>6;
  int m16 = lane&15, quad = lane>>4;
  for (int n0 = wid*16; n0 < Nout; n0 += 64){
    f32x4 acc = {0.f,0.f,0.f,0.f};
    for (int k0=0;k0<K;k0+=32){
      short8 af = *(const short8*)(A + m16*SA + k0 + quad*8);
      short8 bfv = ldw8(W + (size_t)(n0+m16)*K + k0 + quad*8);
      acc = __builtin_amdgcn_mfma_f32_16x16x32_bf16(af, bfv, acc, 0, 0, 0);
    }
    int col = n0 + m16;
    float bv = bias[col];
    #pragma unroll
    for (int r=0;r<4;r++){
      float v = acc[r] + bv;
      if (act) v = gelu_f(v);
      O[(quad*4+r)*SO + col] = f2b(v);
    }
  }
}

#define SP1 136
#define SP2 264
#define SP3 392

// ---------------- edge transformer (per batch): hacc -> hyper_f, V, Kt, qbK ----------------
__global__ __launch_bounds__(256) void k_edge(const float* __restrict__ hacc,
    const float* w_in, const float* b_in, const float* w_out, const float* b_out,
    const float* w1, const float* b1, const float* w2, const float* b2v,
    const float* tg, const float* tb, const float* nhg, const float* nhb,
    const float* hpw, const float* hpb, const float* kvw, const float* kvbias,
    const float* qw, const float* qb,
    bf_t* __restrict__ hfw, bf_t* __restrict__ vws,
    float* __restrict__ Ktg, float* __restrict__ qbK){
  __shared__ __align__(16) bf_t hyp0[16*SP1];
  __shared__ __align__(16) bf_t qkvb[16*SP3];
  __shared__ __align__(16) bf_t aob [16*SP1];
  __shared__ __align__(16) bf_t xnb [16*SP1];
  __shared__ __align__(16) bf_t h1b [16*SP2];
  __shared__ __align__(16) bf_t t2b [16*SP1];
  __shared__ __align__(16) bf_t hfb [16*SP1];
  __shared__ __align__(16) bf_t kvo [16*SP2];
  int b = blockIdx.x, tid = threadIdx.x;

  #pragma unroll
  for (int p=0;p<8;p++){
    int idx = tid + p*256;
    int e = idx>>7, c = idx&127;
    hyp0[e*SP1 + c] = f2b(hacc[(size_t)(b*EE + e)*CC + c]);
  }
  __syncthreads();
  gemm16(hyp0, SP1, w_in, b_in, qkvb, SP3, 384, 128, 0, tid);
  __syncthreads();
  {
    int part = tid&3, hq = tid>>2;
    int h = hq>>4, qi = hq&15;
    int dbase = h*32 + part*8;
    float qv[8];
    #pragma unroll
    for (int j=0;j<8;j++) qv[j] = b2f(qkvb[qi*SP3 + dbase + j]);
    float dot[16];
    #pragma unroll
    for (int kk=0;kk<16;kk++){
      float s = 0.f;
      #pragma unroll
      for (int j=0;j<8;j++) s += qv[j]*b2f(qkvb[kk*SP3 + 128 + dbase + j]);
      dot[kk] = s;
    }
    #pragma unroll
    for (int m=1;m<4;m<<=1){
      #pragma unroll
      for (int kk=0;kk<16;kk++) dot[kk] += __shfl_xor(dot[kk], m, 4);
    }
    const float sc1 = 0.17677669529663687f;
    float mx = -1e30f;
    #pragma unroll
    for (int kk=0;kk<16;kk++){ dot[kk] *= sc1; mx = fmaxf(mx, dot[kk]); }
    float sum = 0.f;
    #pragma unroll
    for (int kk=0;kk<16;kk++){ dot[kk] = __expf(dot[kk]-mx); sum += dot[kk]; }
    float inv = 1.f/sum;
    float ao[8] = {0,0,0,0,0,0,0,0};
    #pragma unroll
    for (int kk=0;kk<16;kk++){
      float p = dot[kk]*inv;
      #pragma unroll
      for (int j=0;j<8;j++) ao[j] += p*b2f(qkvb[kk*SP3 + 256 + dbase + j]);
    }
    #pragma unroll
    for (int j=0;j<8;j++) aob[qi*SP1 + dbase + j] = f2b(ao[j]);
  }
  __syncthreads();
  gemm16(aob, SP1, w_out, b_out, xnb, SP1, 128, 128, 0, tid);
  __syncthreads();
  {
    int e = tid>>4, i = tid&15;
    float v[8]; float s=0.f, q=0.f;
    #pragma unroll
    for (int j=0;j<8;j++){
      int c = i*8+j;
      v[j] = b2f(hyp0[e*SP1+c]) + b2f(xnb[e*SP1+c]);
      s += v[j]; q += v[j]*v[j];
    }
    s = red16(s); q = red16(q);
    float m = s*(1.f/128.f);
    float rs = grs(q*(1.f/128.f) - m*m);
    #pragma unroll
    for (int j=0;j<8;j++){
      int c = i*8+j;
      xnb[e*SP1+c] = f2b((v[j]-m)*rs*tg[c] + tb[c]);
    }
  }
  __syncthreads();
  gemm16(xnb, SP1, w1, b1, h1b, SP2, 256, 128, 1, tid);
  __syncthreads();
  gemm16(h1b, SP2, w2, b2v, aob, SP1, 128, 256, 0, tid);
  __syncthreads();
  {
    int e = tid>>4, i = tid&15;
    float v[8]; float s=0.f, q=0.f;
    #pragma unroll
    for (int j=0;j<8;j++){
      int c = i*8+j;
      v[j] = b2f(xnb[e*SP1+c]) + b2f(aob[e*SP1+c]);
      s += v[j]; q += v[j]*v[j];
    }
    s = red16(s); q = red16(q);
    float m = s*(1.f/128.f);
    float rs = grs(q*(1.f/128.f) - m*m);
    float s2=0.f, q2=0.f;
    #pragma unroll
    for (int j=0;j<8;j++){
      int c = i*8+j;
      v[j] = (v[j]-m)*rs*tg[c] + tb[c];
      s2 += v[j]; q2 += v[j]*v[j];
    }
    s2 = red16(s2); q2 = red16(q2);
    float m2 = s2*(1.f/128.f);
    float rs2 = grs(q2*(1.f/128.f) - m2*m2);
    #pragma unroll
    for (int j=0;j<8;j++){
      int c = i*8+j;
      t2b[e*SP1+c] = f2b((v[j]-m2)*rs2*nhg[c] + nhb[c]);
    }
  }
  __syncthreads();
  gemm16(t2b, SP1, hpw, hpb, hfb, SP1, 128, 128, 1, tid);
  __syncthreads();
  gemm16(hfb, SP1, kvw, kvbias, kvo, SP2, 256, 128, 0, tid);
  __syncthreads();
  #pragma unroll
  for (int p=0;p<8;p++){
    int idx = tid + p*256;
    int e = idx>>7, c = idx&127;
    size_t o = (size_t)(b*EE + e)*CC + c;
    hfw[o] = hfb[e*SP1 + c];
    vws[o] = kvo[e*SP2 + 128 + c];
  }
  #pragma unroll
  for (int p=0;p<8;p++){
    int idx = tid + p*256;
    int e = idx>>7, c = idx&127;
    float s = 0.f;
    for (int d=0; d<128; d++) s += b2f(kvo[e*SP2 + d]) * qw[d*128 + c];
    Ktg[(size_t)(b*EE + e)*CC + c] = s;
  }
  if (tid < 16){
    float s = 0.f;
    for (int d=0; d<128; d++) s += qb[d] * b2f(kvo[tid*SP2 + d]);
    qbK[b*EE + tid] = s;
  }
}

// -------- mega node kernel, MFMA throughout. PRE=1: bf16 weights from ws. --------
template<int PRE>
__global__ __launch_bounds__(256) void k_meganode(
    float* __restrict__ io, const float* __restrict__ sc,
    const bf_t* __restrict__ hf, const bf_t* __restrict__ vw,
    const float* __restrict__ Ktg, const float* __restrict__ qbK,
    const float* __restrict__ nfg, const float* __restrict__ nfb,
    const float* __restrict__ gw, const bf_t* __restrict__ gwb,
    const float* __restrict__ gb,
    const float* __restrict__ glng, const float* __restrict__ glnb,
    const float* __restrict__ npw, const bf_t* __restrict__ npwb,
    const float* __restrict__ npb){
  int tid = threadIdx.x, lane = tid&63, wid = tid>>6;
  int m16 = lane&15, quad = lane>>4;
  int b = blockIdx.y, n0 = blockIdx.x*64;
  __shared__ __align__(16) bf_t xt[64*136];       // 17408: [node][c] bf16
  __shared__ __align__(16) char ctbuf[34816];     // ct bf16 [64][272] / ot f32 [128][68]
  __shared__ __align__(16) bf_t ktT[16*136];      // 4352: [e][c]
  __shared__ __align__(16) bf_t hfT[128*24];      // 6144: [c][e]
  __shared__ __align__(16) bf_t vfT[128*24];      // 6144
  __shared__ __align__(16) bf_t a_sh[64*24];      // 3072: [node][e]
  __shared__ float prm[1040];                     // 4160
  bf_t* ct = (bf_t*)ctbuf;
  float* ot = (float*)ctbuf;
  const short8 z8 = {0,0,0,0,0,0,0,0};

  // ---- staging ----
  #pragma unroll
  for (int p=0;p<8;p++){                          // node tile: c-major f32 -> [n][c] bf16
    int idx = tid + p*256;
    int c = idx>>4, n4 = (idx&15)*4;
    float4 v = *(const float4*)(io + ((size_t)(b*CC + c))*NN + n0 + n4);
    xt[(n4+0)*136 + c] = f2b(v.x);
    xt[(n4+1)*136 + c] = f2b(v.y);
    xt[(n4+2)*136 + c] = f2b(v.z);
    xt[(n4+3)*136 + c] = f2b(v.w);
  }
  #pragma unroll
  for (int p=0;p<2;p++){                          // Kt: f32 [e][c] -> bf16
    int idx = tid + p*256;                        // 0..511
    int e = idx>>5, c4 = (idx&31)*4;
    float4 v = *(const float4*)(Ktg + (size_t)(b*EE + e)*CC + c4);
    *(u32*)&ktT[e*136 + c4]     = pk2(v.x, v.y);
    *(u32*)&ktT[e*136 + c4 + 2] = pk2(v.z, v.w);
  }
  { const u32* hs = (const u32*)(hf + (size_t)b*EE*CC);
    const u32* vs = (const u32*)(vw + (size_t)b*EE*CC);
    #pragma unroll
    for (int p=0;p<4;p++){                        // hf/vf [e][c] bf16 -> [c][e]
      int idx = tid + p*256;                      // 0..1023
      int e = idx>>6, c2 = (idx&63)*2;
      u32 hv = hs[idx], vv = vs[idx];
      hfT[(c2+0)*24 + e] = (bf_t)(hv&0xffffu);
      hfT[(c2+1)*24 + e] = (bf_t)(hv>>16);
      vfT[(c2+0)*24 + e] = (bf_t)(vv&0xffffu);
      vfT[(c2+1)*24 + e] = (bf_t)(vv>>16);
    }
  }
  if (tid < 256){ prm[tid] = nfg[tid]; prm[256+tid] = nfb[tid]; }
  if (tid < 128){ prm[512+tid] = gb[tid]; prm[640+tid] = glng[tid];
                  prm[768+tid] = glnb[tid]; prm[896+tid] = npb[tid]; }
  if (tid < 16) prm[1024+tid] = qbK[b*EE + tid];
  __syncthreads();

  // ---- QK^T dots via MFMA: D[node][e], then softmax over e-lanes ----
  f32x4 dacc = {0.f,0.f,0.f,0.f};
  #pragma unroll
  for (int kk=0;kk<4;kk++){
    short8 a = *(const short8*)(xt + (wid*16+m16)*136 + kk*32 + quad*8);
    short8 bfr = *(const short8*)(ktT + m16*136 + kk*32 + quad*8);
    dacc = __builtin_amdgcn_mfma_f32_16x16x32_bf16(a, bfr, dacc, 0, 0, 0);
  }
  { float qbe = prm[1024 + m16];
    #pragma unroll
    for (int r=0;r<4;r++){
      float v = (dacc[r] + qbe) * 0.08838834764831845f;   // C^-0.5
      float m = v;
      #pragma unroll
      for (int msk=1;msk<16;msk<<=1) m = fmaxf(m, __shfl_xor(m, msk, 16));
      float ex = __expf(v - m);
      float s = ex;
      #pragma unroll
      for (int msk=1;msk<16;msk<<=1) s += __shfl_xor(s, msk, 16);
      a_sh[(wid*16 + quad*4 + r)*24 + m16] = f2b(ex / s);
    }
  }

  // ---- intra = sc@hf, cross = a@vf via MFMA (K=16 padded to 32) ----
  short8 scf = z8, asf = z8;
  if (quad < 2){
    float4 u0 = *(const float4*)(sc + ((size_t)(b*NN + n0 + wid*16 + m16))*EE + quad*8);
    float4 u1 = *(const float4*)(sc + ((size_t)(b*NN + n0 + wid*16 + m16))*EE + quad*8 + 4);
    scf[0]=(short)f2b(u0.x); scf[1]=(short)f2b(u0.y); scf[2]=(short)f2b(u0.z); scf[3]=(short)f2b(u0.w);
    scf[4]=(short)f2b(u1.x); scf[5]=(short)f2b(u1.y); scf[6]=(short)f2b(u1.z); scf[7]=(short)f2b(u1.w);
    asf = *(const short8*)(a_sh + (wid*16+m16)*24 + quad*8);
  }
  f32x4 acc_it[8], acc_cr[8];
  #pragma unroll
  for (int t=0;t<8;t++){
    short8 bh = z8, bv = z8;
    if (quad < 2){
      bh = *(const short8*)(hfT + (t*16+m16)*24 + quad*8);
      bv = *(const short8*)(vfT + (t*16+m16)*24 + quad*8);
    }
    f32x4 zf = {0.f,0.f,0.f,0.f};
    acc_it[t] = __builtin_amdgcn_mfma_f32_16x16x32_bf16(scf, bh, zf, 0, 0, 0);
    acc_cr[t] = __builtin_amdgcn_mfma_f32_16x16x32_bf16(asf, bv, zf, 0, 0, 0);
  }

  // ---- concat-LN (per node over 256 chans) -> ct bf16 [node][272] ----
  { float s4[4]={0,0,0,0}, q4[4]={0,0,0,0};
    #pragma unroll
    for (int t=0;t<8;t++)
      #pragma unroll
      for (int r=0;r<4;r++){
        float a = acc_it[t][r], c = acc_cr[t][r];
        s4[r] += a + c; q4[r] += a*a + c*c;
      }
    #pragma unroll
    for (int r=0;r<4;r++){ s4[r] = red16(s4[r]); q4[r] = red16(q4[r]); }
    #pragma unroll
    for (int r=0;r<4;r++){
      float mean = s4[r]*(1.f/256.f);
      float rstd = grs(q4[r]*(1.f/256.f) - mean*mean);
      int node = wid*16 + quad*4 + r;
      #pragma unroll
      for (int t=0;t<8;t++){
        int ch = t*16 + m16;
        ct[node*272 + ch]       = f2b((acc_it[t][r]-mean)*rstd*prm[ch]     + prm[256+ch]);
        ct[node*272 + 128 + ch] = f2b((acc_cr[t][r]-mean)*rstd*prm[128+ch] + prm[384+ch]);
      }
    }
  }

  // ---- gate GEMM (K=256): A from ct rows, B = gw ----
  short8 af[8];
  #pragma unroll
  for (int kk=0;kk<8;kk++)
    af[kk] = *(const short8*)(ct + (wid*16+m16)*272 + kk*32 + quad*8);
  f32x4 acc_g[8];
  #pragma unroll
  for (int t=0;t<8;t++){
    f32x4 a = {0.f,0.f,0.f,0.f};
    #pragma unroll
    for (int kk=0;kk<8;kk++){
      short8 w8 = PRE ? *(const short8*)(gwb + (size_t)(t*16+m16)*256 + kk*32 + quad*8)
                      : ldw8(gw + (size_t)(t*16+m16)*256 + kk*32 + quad*8);
      a = __builtin_amdgcn_mfma_f32_16x16x32_bf16(af[kk], w8, a, 0, 0, 0);
    }
    acc_g[t] = a;
  }
  __syncthreads();   // all ct reads complete before ot overlay writes

  // ---- gate bias + gate-LN + sigmoid + fuse + residual -> upd into xt ----
  { float s2[4]={0,0,0,0}, q2[4]={0,0,0,0};
    #pragma unroll
    for (int t=0;t<8;t++){
      float bv = prm[512 + t*16 + m16];
      #pragma unroll
      for (int r=0;r<4;r++){
        float v = acc_g[t][r] + bv;
        acc_g[t][r] = v; s2[r] += v; q2[r] += v*v;
      }
    }
    #pragma unroll
    for (int r=0;r<4;r++){ s2[r] = red16(s2[r]); q2[r] = red16(q2[r]); }
    #pragma unroll
    for (int t=0;t<8;t++){
      int col = t*16 + m16;
      float lg = prm[640+col], lb = prm[768+col];
      #pragma unroll
      for (int r=0;r<4;r++){
        float m2 = s2[r]*(1.f/128.f);
        float rs2 = grs(q2[r]*(1.f/128.f) - m2*m2);
        float z = (acc_g[t][r]-m2)*rs2*lg + lb;
        float gs = 1.f/(1.f + __expf(-z));
        int node = wid*16 + quad*4 + r;
        float nld = b2f(xt[node*136 + col]);
        xt[node*136 + col] = f2b(nld + gs*acc_it[t][r] + (1.f-gs)*acc_cr[t][r]);
      }
    }
  }

  // ---- output projection: out[c'][node] = gelu(npw @ upd + npb) ----
  short8 bfu[4];
  #pragma unroll
  for (int kk=0;kk<4;kk++)
    bfu[kk] = *(const short8*)(xt + (wid*16+m16)*136 + kk*32 + quad*8);
  #pragma unroll
  for (int mt=0;mt<8;mt++){
    f32x4 o = {0.f,0.f,0.f,0.f};
    #pragma unroll
    for (int kk=0;kk<4;kk++){
      short8 aw = PRE ? *(const short8*)(npwb + (size_t)(mt*16+m16)*128 + kk*32 + quad*8)
                      : ldw8(npw + (size_t)(mt*16+m16)*128 + kk*32 + quad*8);
      o = __builtin_amdgcn_mfma_f32_16x16x32_bf16(aw, bfu[kk], o, 0, 0, 0);
    }
    #pragma unroll
    for (int r=0;r<4;r++){
      int cp = mt*16 + quad*4 + r;
      ot[cp*68 + wid*16 + m16] = gelu_f(o[r] + prm[896+cp]);
    }
  }
  __syncthreads();
  // coalesced store: [c][64] f32 -> io c-major
  #pragma unroll
  for (int p=0;p<8;p++){
    int idx = tid + p*256;
    int c = idx>>4, n4 = (idx&15)*4;
    float4 v = *(const float4*)&ot[c*68 + n4];
    *(float4*)(io + ((size_t)(b*CC + c))*NN + n0 + n4) = v;
  }
}

extern "C" void kernel_launch(void* const* d_in, const int* in_sizes, int n_in,
                              void* d_out, int out_size, void* d_ws, size_t ws_size,
                              hipStream_t stream){
  (void)in_sizes; (void)n_in; (void)out_size;
  const float* fm   = (const float*)d_in[0];
  const float* sc   = (const float*)d_in[1];
  const float* npg  = (const float*)d_in[2];
  const float* npb_ = (const float*)d_in[3];
  const float* w_in = (const float*)d_in[4];
  const float* b_in = (const float*)d_in[5];
  const float* w_out= (const float*)d_in[6];
  const float* b_out= (const float*)d_in[7];
  const float* w1   = (const float*)d_in[8];
  const float* b1   = (const float*)d_in[9];
  const float* w2   = (const float*)d_in[10];
  const float* b2v  = (const float*)d_in[11];
  const float* tg   = (const float*)d_in[12];
  const float* tb   = (const float*)d_in[13];
  const float* nhg  = (const float*)d_in[14];
  const float* nhb  = (const float*)d_in[15];
  const float* hpw  = (const float*)d_in[16];
  const float* hpb  = (const float*)d_in[17];
  const float* qw   = (const float*)d_in[18];
  const float* qb   = (const float*)d_in[19];
  const float* kvw  = (const float*)d_in[20];
  const float* kvb  = (const float*)d_in[21];
  const float* nfg  = (const float*)d_in[22];
  const float* nfb  = (const float*)d_in[23];
  const float* gw   = (const float*)d_in[24];
  const float* gb   = (const float*)d_in[25];
  const float* glng = (const float*)d_in[26];
  const float* glnb = (const float*)d_in[27];
  const float* npw  = (const float*)d_in[28];
  const float* npb2 = (const float*)d_in[29];

  float* nln = (float*)d_out;   // node tensor fp32 c-major [B,C,N] lives in d_out

  char* w = (char*)d_ws;
  float* hacc = (float*)(w);                   //  65,536 B
  float* Ktg  = (float*)(w + 65536);           //  65,536 B
  float* qbK  = (float*)(w + 131072);          //     512 B
  bf_t*  hfw  = (bf_t*) (w + 131584);          //  32,768 B
  bf_t*  vws  = (bf_t*) (w + 164352);          //  32,768 B (end 197,120)
  bf_t*  gwb  = (bf_t*) (w + 197120);          //  65,536 B (PRE only)
  bf_t*  npwb = (bf_t*) (w + 262656);          //  32,768 B (end 295,424)
  bool pre = (ws_size >= (size_t)295424);

  k_zero  <<<dim3(64),   dim3(256), 0, stream>>>(hacc);
  k_ln_agg<<<dim3(36,8), dim3(256), 0, stream>>>(fm, npg, npb_, sc, nln, hacc);
  k_edge  <<<dim3(8),    dim3(256), 0, stream>>>(hacc, w_in,b_in,w_out,b_out,
                                                 w1,b1,w2,b2v, tg,tb, nhg,nhb,
                                                 hpw,hpb, kvw,kvb, qw,qb,
                                                 hfw, vws, Ktg, qbK);
  if (pre){
    k_cvtw<<<dim3(64), dim3(256), 0, stream>>>(gw, npw, gwb, npwb);
    k_meganode<1><<<dim3(144,8), dim3(256), 0, stream>>>(nln, sc, hfw, vws, Ktg, qbK,
                                                         nfg, nfb, gw, gwb, gb,
                                                         glng, glnb, npw, npwb, npb2);
  } else {
    k_meganode<0><<<dim3(144,8), dim3(256), 0, stream>>>(nln, sc, hfw, vws, Ktg, qbK,
                                                         nfg, nfb, gw, gwb, gb,
                                                         glng, glnb, npw, npwb, npb2);
  }
}

// Round 8
// 299.341 us; speedup vs baseline: 2.2129x; 1.0406x over previous
//
#include <hip/hip_runtime.h>

typedef unsigned short bf_t;
typedef unsigned int u32;
typedef short short8 __attribute__((ext_vector_type(8)));
typedef float f32x4 __attribute__((ext_vector_type(4)));

#define NB 8
#define CC 128
#define NN 9216
#define EE 16

__device__ __forceinline__ float b2f(bf_t u){ return __uint_as_float(((u32)u)<<16); }
__device__ __forceinline__ bf_t f2b(float f){
  u32 u = __float_as_uint(f);
  u = (u + 0x7fffu + ((u>>16)&1u)) >> 16;
  return (bf_t)u;
}
__device__ __forceinline__ float gelu_f(float x){ return 0.5f*x*(1.f+erff(x*0.70710678118654752f)); }
__device__ __forceinline__ float red16(float v){
  #pragma unroll
  for (int m=1;m<16;m<<=1) v += __shfl_xor(v, m, 16);
  return v;
}
__device__ __forceinline__ float grs(float var){
  return rsqrtf(fmaxf(var + 1e-5f, 1e-8f));
}
// 8 consecutive fp32 -> bf16x8 MFMA fragment (fallback / on-the-fly path)
__device__ __forceinline__ short8 ldw8(const float* __restrict__ p){
  float4 a = *(const float4*)p;
  float4 b = *(const float4*)(p+4);
  short8 o;
  o[0]=(short)f2b(a.x); o[1]=(short)f2b(a.y); o[2]=(short)f2b(a.z); o[3]=(short)f2b(a.w);
  o[4]=(short)f2b(b.x); o[5]=(short)f2b(b.y); o[6]=(short)f2b(b.z); o[7]=(short)f2b(b.w);
  return o;
}

// ---------------- zero hacc (+ optional weight pre-convert) ----------------
template<int PRE>
__global__ __launch_bounds__(256) void k_pre(float* __restrict__ hacc,
                                             const float* __restrict__ gw,
                                             const float* __restrict__ npw,
                                             bf_t* __restrict__ gwb,
                                             bf_t* __restrict__ npwb){
  int i = blockIdx.x*256 + threadIdx.x;     // 64 blocks -> 16384
  hacc[i] = 0.f;
  if (PRE){
    gwb[i]       = f2b(gw[i]);
    gwb[i+16384] = f2b(gw[i+16384]);
    npwb[i]      = f2b(npw[i]);
  }
}

// ---- node LN (over c) + hyperedge aggregation, fp32 I/O, 1 tile/block ----
__global__ __launch_bounds__(256) void k_ln_agg(const float* __restrict__ fm,
                                                const float* __restrict__ g,
                                                const float* __restrict__ bb,
                                                const float* __restrict__ sc,
                                                float* __restrict__ nln,
                                                float* __restrict__ hacc){
  int b = blockIdx.y, n0 = blockIdx.x*64, tid = threadIdx.x;
  __shared__ float xs[128*65];              // [c][n] tile, pad 65
  __shared__ float scs[64][17];             // [n][e]
  __shared__ float ps[4][64], pq[4][64], mrs[2][64];
  const float* base = fm + (size_t)b*CC*NN + n0;
  #pragma unroll
  for (int p=0;p<8;p++){
    int idx = tid + p*256;                  // 0..2047 float4s
    int c = idx>>4, n4 = (idx&15)*4;
    float4 v = *(const float4*)(base + (size_t)c*NN + n4);
    xs[c*65 + n4+0] = v.x; xs[c*65 + n4+1] = v.y;
    xs[c*65 + n4+2] = v.z; xs[c*65 + n4+3] = v.w;
  }
  { int n = tid>>2, e4 = (tid&3)*4;
    float4 sv = *(const float4*)(sc + ((size_t)(b*NN + n0 + n))*EE + e4);
    scs[n][e4+0] = sv.x; scs[n][e4+1] = sv.y;
    scs[n][e4+2] = sv.z; scs[n][e4+3] = sv.w;
  }
  __syncthreads();
  { int cg = tid>>6, n = tid&63;
    float s=0.f, q=0.f;
    #pragma unroll
    for (int c=0;c<32;c++){ float v = xs[(cg*32+c)*65 + n]; s+=v; q+=v*v; }
    ps[cg][n]=s; pq[cg][n]=q;
  }
  __syncthreads();
  if (tid < 64){
    float S = ps[0][tid]+ps[1][tid]+ps[2][tid]+ps[3][tid];
    float Q = pq[0][tid]+pq[1][tid]+pq[2][tid]+pq[3][tid];
    float m = S*(1.f/128.f);
    mrs[0][tid] = m; mrs[1][tid] = grs(Q*(1.f/128.f) - m*m);
  }
  __syncthreads();
  #pragma unroll
  for (int p=0;p<8;p++){
    int idx = tid + p*256;
    int c = idx>>4, n4 = (idx&15)*4;
    float gv = g[c], bv = bb[c];
    float4 o;
    float v0 = (xs[c*65+n4+0]-mrs[0][n4+0])*mrs[1][n4+0]*gv + bv;
    float v1 = (xs[c*65+n4+1]-mrs[0][n4+1])*mrs[1][n4+1]*gv + bv;
    float v2 = (xs[c*65+n4+2]-mrs[0][n4+2])*mrs[1][n4+2]*gv + bv;
    float v3 = (xs[c*65+n4+3]-mrs[0][n4+3])*mrs[1][n4+3]*gv + bv;
    o.x=v0; o.y=v1; o.z=v2; o.w=v3;
    xs[c*65+n4+0]=v0; xs[c*65+n4+1]=v1; xs[c*65+n4+2]=v2; xs[c*65+n4+3]=v3;
    *(float4*)(nln + ((size_t)(b*CC + c))*NN + n0 + n4) = o;
  }
  __syncthreads();
  { int cp = tid&63, eh = tid>>6;
    float a0[4]={0,0,0,0}, a1[4]={0,0,0,0};
    for (int n=0;n<64;n++){
      float x0 = xs[cp*65 + n], x1 = xs[(cp+64)*65 + n];
      #pragma unroll
      for (int j=0;j<4;j++){
        float se = scs[n][eh*4+j];
        a0[j] += se*x0; a1[j] += se*x1;
      }
    }
    #pragma unroll
    for (int j=0;j<4;j++){
      float* hb = hacc + (size_t)(b*EE + eh*4 + j)*CC;
      atomicAdd(hb + cp, a0[j]);
      atomicAdd(hb + cp + 64, a1[j]);
    }
  }
}

// ---------------- in-LDS 16-row MFMA GEMM helper (templated, fully unrolled) ----------------
template<int K, int NOUT, int ACT>
__device__ __forceinline__ void gemm16(const bf_t* A, int SA,
                                       const float* __restrict__ W,
                                       const float* __restrict__ bias,
                                       bf_t* O, int SO, int tid){
  int lane = tid&63, wid = tid>>6;
  int m16 = lane&15, quad = lane>>4;
  #pragma unroll
  for (int u=0; u<NOUT/64; u++){
    int n0 = u*64 + wid*16;
    f32x4 acc = {0.f,0.f,0.f,0.f};
    #pragma unroll
    for (int k0=0;k0<K;k0+=32){
      short8 af = *(const short8*)(A + m16*SA + k0 + quad*8);
      short8 bfv = ldw8(W + (size_t)(n0+m16)*K + k0 + quad*8);
      acc = __builtin_amdgcn_mfma_f32_16x16x32_bf16(af, bfv, acc, 0, 0, 0);
    }
    int col = n0 + m16;
    float bv = bias[col];
    #pragma unroll
    for (int r=0;r<4;r++){
      float v = acc[r] + bv;
      if (ACT) v = gelu_f(v);
      O[(quad*4+r)*SO + col] = f2b(v);
    }
  }
}

#define SP1 136
#define SP2 264
#define SP3 392

// ---------------- edge transformer (per batch): hacc -> hyper_f, V, Ktgb, qbK ----------------
__global__ __launch_bounds__(256) void k_edge(const float* __restrict__ hacc,
    const float* w_in, const float* b_in, const float* w_out, const float* b_out,
    const float* w1, const float* b1, const float* w2, const float* b2v,
    const float* tg, const float* tb, const float* nhg, const float* nhb,
    const float* hpw, const float* hpb, const float* kvw, const float* kvbias,
    const float* qw, const float* qb,
    bf_t* __restrict__ hfw, bf_t* __restrict__ vws,
    bf_t* __restrict__ Ktgb, float* __restrict__ qbK){
  __shared__ __align__(16) bf_t hyp0[16*SP1];
  __shared__ __align__(16) bf_t qkvb[16*SP3];
  __shared__ __align__(16) bf_t aob [16*SP1];
  __shared__ __align__(16) bf_t xnb [16*SP1];
  __shared__ __align__(16) bf_t h1b [16*SP2];
  __shared__ __align__(16) bf_t t2b [16*SP1];
  __shared__ __align__(16) bf_t hfb [16*SP1];
  __shared__ __align__(16) bf_t kvo [16*SP2];
  int b = blockIdx.x, tid = threadIdx.x;
  int lane = tid&63, wid = tid>>6, m16 = lane&15, quad = lane>>4;

  #pragma unroll
  for (int p=0;p<8;p++){
    int idx = tid + p*256;
    int e = idx>>7, c = idx&127;
    hyp0[e*SP1 + c] = f2b(hacc[(size_t)(b*EE + e)*CC + c]);
  }
  __syncthreads();
  gemm16<128,384,0>(hyp0, SP1, w_in, b_in, qkvb, SP3, tid);
  __syncthreads();
  {
    int part = tid&3, hq = tid>>2;
    int h = hq>>4, qi = hq&15;
    int dbase = h*32 + part*8;
    float qv[8];
    #pragma unroll
    for (int j=0;j<8;j++) qv[j] = b2f(qkvb[qi*SP3 + dbase + j]);
    float dot[16];
    #pragma unroll
    for (int kk=0;kk<16;kk++){
      float s = 0.f;
      #pragma unroll
      for (int j=0;j<8;j++) s += qv[j]*b2f(qkvb[kk*SP3 + 128 + dbase + j]);
      dot[kk] = s;
    }
    #pragma unroll
    for (int m=1;m<4;m<<=1){
      #pragma unroll
      for (int kk=0;kk<16;kk++) dot[kk] += __shfl_xor(dot[kk], m, 4);
    }
    const float sc1 = 0.17677669529663687f;
    float mx = -1e30f;
    #pragma unroll
    for (int kk=0;kk<16;kk++){ dot[kk] *= sc1; mx = fmaxf(mx, dot[kk]); }
    float sum = 0.f;
    #pragma unroll
    for (int kk=0;kk<16;kk++){ dot[kk] = __expf(dot[kk]-mx); sum += dot[kk]; }
    float inv = 1.f/sum;
    float ao[8] = {0,0,0,0,0,0,0,0};
    #pragma unroll
    for (int kk=0;kk<16;kk++){
      float p = dot[kk]*inv;
      #pragma unroll
      for (int j=0;j<8;j++) ao[j] += p*b2f(qkvb[kk*SP3 + 256 + dbase + j]);
    }
    #pragma unroll
    for (int j=0;j<8;j++) aob[qi*SP1 + dbase + j] = f2b(ao[j]);
  }
  __syncthreads();
  gemm16<128,128,0>(aob, SP1, w_out, b_out, xnb, SP1, tid);
  __syncthreads();
  {
    int e = tid>>4, i = tid&15;
    float v[8]; float s=0.f, q=0.f;
    #pragma unroll
    for (int j=0;j<8;j++){
      int c = i*8+j;
      v[j] = b2f(hyp0[e*SP1+c]) + b2f(xnb[e*SP1+c]);
      s += v[j]; q += v[j]*v[j];
    }
    s = red16(s); q = red16(q);
    float m = s*(1.f/128.f);
    float rs = grs(q*(1.f/128.f) - m*m);
    #pragma unroll
    for (int j=0;j<8;j++){
      int c = i*8+j;
      xnb[e*SP1+c] = f2b((v[j]-m)*rs*tg[c] + tb[c]);
    }
  }
  __syncthreads();
  gemm16<128,256,1>(xnb, SP1, w1, b1, h1b, SP2, tid);
  __syncthreads();
  gemm16<256,128,0>(h1b, SP2, w2, b2v, aob, SP1, tid);
  __syncthreads();
  {
    int e = tid>>4, i = tid&15;
    float v[8]; float s=0.f, q=0.f;
    #pragma unroll
    for (int j=0;j<8;j++){
      int c = i*8+j;
      v[j] = b2f(xnb[e*SP1+c]) + b2f(aob[e*SP1+c]);
      s += v[j]; q += v[j]*v[j];
    }
    s = red16(s); q = red16(q);
    float m = s*(1.f/128.f);
    float rs = grs(q*(1.f/128.f) - m*m);
    float s2=0.f, q2=0.f;
    #pragma unroll
    for (int j=0;j<8;j++){
      int c = i*8+j;
      v[j] = (v[j]-m)*rs*tg[c] + tb[c];
      s2 += v[j]; q2 += v[j]*v[j];
    }
    s2 = red16(s2); q2 = red16(q2);
    float m2 = s2*(1.f/128.f);
    float rs2 = grs(q2*(1.f/128.f) - m2*m2);
    #pragma unroll
    for (int j=0;j<8;j++){
      int c = i*8+j;
      t2b[e*SP1+c] = f2b((v[j]-m2)*rs2*nhg[c] + nhb[c]);
    }
  }
  __syncthreads();
  gemm16<128,128,1>(t2b, SP1, hpw, hpb, hfb, SP1, tid);
  __syncthreads();
  gemm16<128,256,0>(hfb, SP1, kvw, kvbias, kvo, SP2, tid);
  __syncthreads();
  #pragma unroll
  for (int p=0;p<8;p++){
    int idx = tid + p*256;
    int e = idx>>7, c = idx&127;
    size_t o = (size_t)(b*EE + e)*CC + c;
    hfw[o] = hfb[e*SP1 + c];
    vws[o] = kvo[e*SP2 + 128 + c];
  }
  // Kt[e][c] = sum_d K[e][d]*qw[d][c] via MFMA, bf16 out
  #pragma unroll
  for (int u=0;u<2;u++){
    int n0 = u*64 + wid*16;
    f32x4 acc = {0.f,0.f,0.f,0.f};
    #pragma unroll
    for (int k0=0;k0<128;k0+=32){
      short8 a = *(const short8*)(kvo + m16*SP2 + k0 + quad*8);
      short8 bq;
      #pragma unroll
      for (int j=0;j<8;j++)
        bq[j] = (short)f2b(qw[(size_t)(k0+quad*8+j)*128 + n0+m16]);
      acc = __builtin_amdgcn_mfma_f32_16x16x32_bf16(a, bq, acc, 0, 0, 0);
    }
    #pragma unroll
    for (int r=0;r<4;r++)
      Ktgb[(size_t)(b*EE + quad*4 + r)*CC + n0 + m16] = f2b(acc[r]);
  }
  // qbK[e] = qb . K[e]
  { int e = tid>>4, i = tid&15;
    float s = 0.f;
    #pragma unroll
    for (int j=0;j<8;j++) s += qb[i*8+j]*b2f(kvo[e*SP2 + i*8+j]);
    s = red16(s);
    if (i == 0) qbK[b*EE + e] = s;
  }
}

// -------- mega node kernel, 49.4 KB LDS -> 3 blocks/CU --------
template<int PRE>
__global__ __launch_bounds__(256,3) void k_meganode(
    float* __restrict__ io, const float* __restrict__ sc,
    const bf_t* __restrict__ hf, const bf_t* __restrict__ vw,
    const bf_t* __restrict__ ktg, const float* __restrict__ qbK,
    const float* __restrict__ nfg, const float* __restrict__ nfb,
    const float* __restrict__ gw, const bf_t* __restrict__ gwb,
    const float* __restrict__ gb,
    const float* __restrict__ glng, const float* __restrict__ glnb,
    const float* __restrict__ npw, const bf_t* __restrict__ npwb,
    const float* __restrict__ npb){
  int tid = threadIdx.x, lane = tid&63, wid = tid>>6;
  int m16 = lane&15, quad = lane>>4;
  int b = blockIdx.y, n0 = blockIdx.x*64;
  __shared__ __align__(16) char sm[49408];
  bf_t* xt  = (bf_t*)(sm);            // [64][136] 17,408
  bf_t* ktT = (bf_t*)(sm + 17408);    // [16][136]  4,352
  bf_t* ct  = (bf_t*)(sm + 21760);    // [64][136] 17,408 (A-frag staging, 2 passes)
  bf_t* hfT = (bf_t*)(sm + 39168);    // [128][16]  4,096
  bf_t* vfT = (bf_t*)(sm + 43264);    // [128][16]  4,096
  bf_t* ash = (bf_t*)(sm + 47360);    // [64][16]   2,048
  float* ot = (float*)(sm);           // [128][68] f32 34,816 — overlays xt+ktT+ct (dead)
  const short8 z8 = {0,0,0,0,0,0,0,0};

  // ---- staging ----
  #pragma unroll
  for (int p=0;p<8;p++){                          // node tile: c-major f32 -> [n][c] bf16
    int idx = tid + p*256;
    int c = idx>>4, n4 = (idx&15)*4;
    float4 v = *(const float4*)(io + ((size_t)(b*CC + c))*NN + n0 + n4);
    xt[(n4+0)*136 + c] = f2b(v.x);
    xt[(n4+1)*136 + c] = f2b(v.y);
    xt[(n4+2)*136 + c] = f2b(v.z);
    xt[(n4+3)*136 + c] = f2b(v.w);
  }
  { const u32* kp = (const u32*)(ktg + (size_t)b*EE*CC);
    #pragma unroll
    for (int p=0;p<4;p++){                        // Ktgb bf16 [e][c]
      int idx = tid + p*256;                      // 0..1023 dwords
      int e = idx>>6, c2 = (idx&63)*2;
      *(u32*)&ktT[e*136 + c2] = kp[idx];
    }
  }
  { const u32* hs = (const u32*)(hf + (size_t)b*EE*CC);
    const u32* vs = (const u32*)(vw + (size_t)b*EE*CC);
    #pragma unroll
    for (int p=0;p<4;p++){                        // hf/vf [e][c] bf16 -> [c][e]
      int idx = tid + p*256;
      int e = idx>>6, c2 = (idx&63)*2;
      u32 hv = hs[idx], vv = vs[idx];
      hfT[(c2+0)*16 + e] = (bf_t)(hv&0xffffu);
      hfT[(c2+1)*16 + e] = (bf_t)(hv>>16);
      vfT[(c2+0)*16 + e] = (bf_t)(vv&0xffffu);
      vfT[(c2+1)*16 + e] = (bf_t)(vv>>16);
    }
  }
  __syncthreads();

  // ---- QK^T via MFMA: D[node=quad*4+r(+wid*16)][e=m16]; softmax over e ----
  f32x4 dacc = {0.f,0.f,0.f,0.f};
  #pragma unroll
  for (int kk=0;kk<4;kk++){
    short8 a = *(const short8*)(xt + (wid*16+m16)*136 + kk*32 + quad*8);
    short8 bfr = *(const short8*)(ktT + m16*136 + kk*32 + quad*8);
    dacc = __builtin_amdgcn_mfma_f32_16x16x32_bf16(a, bfr, dacc, 0, 0, 0);
  }
  { float qbe = qbK[b*EE + m16];
    #pragma unroll
    for (int r=0;r<4;r++){
      float v = (dacc[r] + qbe) * 0.08838834764831845f;   // C^-0.5
      float m = v;
      #pragma unroll
      for (int msk=1;msk<16;msk<<=1) m = fmaxf(m, __shfl_xor(m, msk, 16));
      float ex = __expf(v - m);
      float s = ex;
      #pragma unroll
      for (int msk=1;msk<16;msk<<=1) s += __shfl_xor(s, msk, 16);
      ash[(wid*16 + quad*4 + r)*16 + m16] = f2b(ex / s);
    }
  }

  // ---- intra = sc@hf, cross = a@vf via MFMA (K=16 in lower half) ----
  short8 scf = z8, asf = z8;
  if (quad < 2){
    const float* sp = sc + ((size_t)(b*NN + n0 + wid*16 + m16))*EE + quad*8;
    float4 u0 = *(const float4*)sp;
    float4 u1 = *(const float4*)(sp+4);
    scf[0]=(short)f2b(u0.x); scf[1]=(short)f2b(u0.y); scf[2]=(short)f2b(u0.z); scf[3]=(short)f2b(u0.w);
    scf[4]=(short)f2b(u1.x); scf[5]=(short)f2b(u1.y); scf[6]=(short)f2b(u1.z); scf[7]=(short)f2b(u1.w);
    asf = *(const short8*)(ash + (wid*16+m16)*16 + quad*8);
  }
  f32x4 acc_it[8], acc_cr[8];
  #pragma unroll
  for (int t=0;t<8;t++){
    short8 bh = z8, bv = z8;
    if (quad < 2){
      bh = *(const short8*)(hfT + (t*16+m16)*16 + quad*8);
      bv = *(const short8*)(vfT + (t*16+m16)*16 + quad*8);
    }
    f32x4 zf = {0.f,0.f,0.f,0.f};
    acc_it[t] = __builtin_amdgcn_mfma_f32_16x16x32_bf16(scf, bh, zf, 0, 0, 0);
    acc_cr[t] = __builtin_amdgcn_mfma_f32_16x16x32_bf16(asf, bv, zf, 0, 0, 0);
  }

  // ---- concat-LN stats (256 chans/node) ----
  float mean4[4], rstd4[4];
  { float s4[4]={0,0,0,0}, q4[4]={0,0,0,0};
    #pragma unroll
    for (int t=0;t<8;t++)
      #pragma unroll
      for (int r=0;r<4;r++){
        float a = acc_it[t][r], c = acc_cr[t][r];
        s4[r] += a + c; q4[r] += a*a + c*c;
      }
    #pragma unroll
    for (int r=0;r<4;r++){
      s4[r] = red16(s4[r]); q4[r] = red16(q4[r]);
      mean4[r] = s4[r]*(1.f/256.f);
      rstd4[r] = grs(q4[r]*(1.f/256.f) - mean4[r]*mean4[r]);
    }
  }
  // ---- gate A fragments via ct, two half-channel passes (wave-private rows) ----
  short8 af[8];
  #pragma unroll
  for (int r=0;r<4;r++){
    int node = wid*16 + quad*4 + r;
    #pragma unroll
    for (int t=0;t<8;t++){
      int ch = t*16 + m16;
      ct[node*136 + ch] = f2b((acc_it[t][r]-mean4[r])*rstd4[r]*nfg[ch] + nfb[ch]);
    }
  }
  #pragma unroll
  for (int kk=0;kk<4;kk++)
    af[kk] = *(const short8*)(ct + (wid*16+m16)*136 + kk*32 + quad*8);
  #pragma unroll
  for (int r=0;r<4;r++){
    int node = wid*16 + quad*4 + r;
    #pragma unroll
    for (int t=0;t<8;t++){
      int ch = t*16 + m16;
      ct[node*136 + ch] = f2b((acc_cr[t][r]-mean4[r])*rstd4[r]*nfg[128+ch] + nfb[128+ch]);
    }
  }
  #pragma unroll
  for (int kk=0;kk<4;kk++)
    af[4+kk] = *(const short8*)(ct + (wid*16+m16)*136 + kk*32 + quad*8);

  // ---- gate GEMM (K=256) ----
  f32x4 acc_g[8];
  #pragma unroll
  for (int t=0;t<8;t++){
    f32x4 a = {0.f,0.f,0.f,0.f};
    #pragma unroll
    for (int kk=0;kk<8;kk++){
      short8 w8 = PRE ? *(const short8*)(gwb + (size_t)(t*16+m16)*256 + kk*32 + quad*8)
                      : ldw8(gw + (size_t)(t*16+m16)*256 + kk*32 + quad*8);
      a = __builtin_amdgcn_mfma_f32_16x16x32_bf16(af[kk], w8, a, 0, 0, 0);
    }
    acc_g[t] = a;
  }

  // ---- gate bias + gate-LN + sigmoid + fuse + residual -> upd into xt ----
  { float s2[4]={0,0,0,0}, q2[4]={0,0,0,0};
    #pragma unroll
    for (int t=0;t<8;t++){
      float bv = gb[t*16+m16];
      #pragma unroll
      for (int r=0;r<4;r++){
        float v = acc_g[t][r] + bv;
        acc_g[t][r] = v; s2[r] += v; q2[r] += v*v;
      }
    }
    #pragma unroll
    for (int r=0;r<4;r++){ s2[r] = red16(s2[r]); q2[r] = red16(q2[r]); }
    #pragma unroll
    for (int t=0;t<8;t++){
      int col = t*16 + m16;
      float lg = glng[col], lb = glnb[col];
      #pragma unroll
      for (int r=0;r<4;r++){
        float m2 = s2[r]*(1.f/128.f);
        float rs2 = grs(q2[r]*(1.f/128.f) - m2*m2);
        float z = (acc_g[t][r]-m2)*rs2*lg + lb;
        float gs = 1.f/(1.f + __expf(-z));
        int node = wid*16 + quad*4 + r;
        float nld = b2f(xt[node*136 + col]);
        xt[node*136 + col] = f2b(nld + gs*acc_it[t][r] + (1.f-gs)*acc_cr[t][r]);
      }
    }
  }

  // ---- output projection frags from xt (own rows), then barrier, then ot overlay ----
  short8 bfu[4];
  #pragma unroll
  for (int kk=0;kk<4;kk++)
    bfu[kk] = *(const short8*)(xt + (wid*16+m16)*136 + kk*32 + quad*8);
  __syncthreads();   // all waves done with xt/ct/ktT before ot writes
  #pragma unroll
  for (int mt=0;mt<8;mt++){
    f32x4 o = {0.f,0.f,0.f,0.f};
    #pragma unroll
    for (int kk=0;kk<4;kk++){
      short8 aw = PRE ? *(const short8*)(npwb + (size_t)(mt*16+m16)*128 + kk*32 + quad*8)
                      : ldw8(npw + (size_t)(mt*16+m16)*128 + kk*32 + quad*8);
      o = __builtin_amdgcn_mfma_f32_16x16x32_bf16(aw, bfu[kk], o, 0, 0, 0);
    }
    #pragma unroll
    for (int r=0;r<4;r++){
      int cp = mt*16 + quad*4 + r;
      ot[cp*68 + wid*16 + m16] = gelu_f(o[r] + npb[cp]);
    }
  }
  __syncthreads();
  #pragma unroll
  for (int p=0;p<8;p++){
    int idx = tid + p*256;
    int c = idx>>4, n4 = (idx&15)*4;
    float4 v = *(const float4*)&ot[c*68 + n4];
    *(float4*)(io + ((size_t)(b*CC + c))*NN + n0 + n4) = v;
  }
}

extern "C" void kernel_launch(void* const* d_in, const int* in_sizes, int n_in,
                              void* d_out, int out_size, void* d_ws, size_t ws_size,
                              hipStream_t stream){
  (void)in_sizes; (void)n_in; (void)out_size;
  const float* fm   = (const float*)d_in[0];
  const float* sc   = (const float*)d_in[1];
  const float* npg  = (const float*)d_in[2];
  const float* npb_ = (const float*)d_in[3];
  const float* w_in = (const float*)d_in[4];
  const float* b_in = (const float*)d_in[5];
  const float* w_out= (const float*)d_in[6];
  const float* b_out= (const float*)d_in[7];
  const float* w1   = (const float*)d_in[8];
  const float* b1   = (const float*)d_in[9];
  const float* w2   = (const float*)d_in[10];
  const float* b2v  = (const float*)d_in[11];
  const float* tg   = (const float*)d_in[12];
  const float* tb   = (const float*)d_in[13];
  const float* nhg  = (const float*)d_in[14];
  const float* nhb  = (const float*)d_in[15];
  const float* hpw  = (const float*)d_in[16];
  const float* hpb  = (const float*)d_in[17];
  const float* qw   = (const float*)d_in[18];
  const float* qb   = (const float*)d_in[19];
  const float* kvw  = (const float*)d_in[20];
  const float* kvb  = (const float*)d_in[21];
  const float* nfg  = (const float*)d_in[22];
  const float* nfb  = (const float*)d_in[23];
  const float* gw   = (const float*)d_in[24];
  const float* gb   = (const float*)d_in[25];
  const float* glng = (const float*)d_in[26];
  const float* glnb = (const float*)d_in[27];
  const float* npw  = (const float*)d_in[28];
  const float* npb2 = (const float*)d_in[29];

  float* nln = (float*)d_out;   // node tensor fp32 c-major [B,C,N] lives in d_out

  // ws layout — FIXED: Ktgb needs 32,768 B ([8][16][128] bf16), was 4,096.
  char* w = (char*)d_ws;
  float* hacc = (float*)(w);                   //  65,536 B
  float* qbK  = (float*)(w + 65536);           //     512 B
  bf_t*  hfw  = (bf_t*) (w + 66048);           //  32,768 B
  bf_t*  vws  = (bf_t*) (w + 98816);           //  32,768 B
  bf_t*  Ktgb = (bf_t*) (w + 131584);          //  32,768 B (end 164,352)
  bf_t*  gwb  = (bf_t*) (w + 164352);          //  65,536 B (PRE only)
  bf_t*  npwb = (bf_t*) (w + 229888);          //  32,768 B (end 262,656)
  bool pre = (ws_size >= (size_t)262656);

  if (pre) k_pre<1><<<dim3(64), dim3(256), 0, stream>>>(hacc, gw, npw, gwb, npwb);
  else     k_pre<0><<<dim3(64), dim3(256), 0, stream>>>(hacc, gw, npw, gwb, npwb);
  k_ln_agg<<<dim3(144,8), dim3(256), 0, stream>>>(fm, npg, npb_, sc, nln, hacc);
  k_edge  <<<dim3(8),     dim3(256), 0, stream>>>(hacc, w_in,b_in,w_out,b_out,
                                                  w1,b1,w2,b2v, tg,tb, nhg,nhb,
                                                  hpw,hpb, kvw,kvb, qw,qb,
                                                  hfw, vws, Ktgb, qbK);
  if (pre)
    k_meganode<1><<<dim3(144,8), dim3(256), 0, stream>>>(nln, sc, hfw, vws, Ktgb, qbK,
                                                         nfg, nfb, gw, gwb, gb,
                                                         glng, glnb, npw, npwb, npb2);
  else
    k_meganode<0><<<dim3(144,8), dim3(256), 0, stream>>>(nln, sc, hfw, vws, Ktgb, qbK,
                                                         nfg, nfb, gw, gwb, gb,
                                                         glng, glnb, npw, npwb, npb2);
}